// Round 11
// baseline (312.716 us; speedup 1.0000x reference)
//
#include <hip/hip_runtime.h>
#include <hip/hip_bf16.h>
#include <math.h>

// Problem constants (CausalSelfAttention_84928683311105)
#define B_  2
#define T_  2048
#define C_  2048
#define NH_ 16
#define NKV_ 4
#define HD_ 128
#define NREP_ (NH_/NKV_)     // 4

// fused QKV output layout: [B*T, 3072] ; q @ 0, k @ 2048, v @ 2560
#define QKVLD 3072
#define KOFF  2048
#define VOFF  2560

// q scale: (1/sqrt(d))^2 folded = 1/128, times log2(e) so scores are in
// log2 units and softmax exp is a single native v_exp_f32.
#define QSCALE 0.01127105500694502f

// fast exp2: bare v_exp_f32 when the builtin exists (libm exp2f adds guards)
#if defined(__has_builtin)
# if __has_builtin(__builtin_amdgcn_exp2f)
#  define EXP2F(x) __builtin_amdgcn_exp2f(x)
# else
#  define EXP2F(x) exp2f(x)
# endif
#else
# define EXP2F(x) exp2f(x)
#endif

typedef __bf16 bf16x8 __attribute__((ext_vector_type(8)));
typedef float  f32x4  __attribute__((ext_vector_type(4)));
typedef float  f32x16 __attribute__((ext_vector_type(16)));

__device__ inline void gload_lds16(const void* g, void* l) {
    __builtin_amdgcn_global_load_lds((const __attribute__((address_space(1))) void*)g,
                                     (__attribute__((address_space(3))) void*)l, 16, 0, 0);
}

// ---------------------------------------------------------------------------
// prep: cast_bf16 + wtrans_qkv + wtrans(Wp) fused into one launch.
// ---------------------------------------------------------------------------
__global__ __launch_bounds__(256) void prep(const float* __restrict__ x,
                                            const float* __restrict__ Wq,
                                            const float* __restrict__ Wk,
                                            const float* __restrict__ Wv,
                                            const float* __restrict__ Wp,
                                            __bf16* __restrict__ xb,
                                            __bf16* __restrict__ wqkvT,
                                            __bf16* __restrict__ wpT)
{
    __shared__ float tl[32][33];
    const int bx  = blockIdx.x;
    const int tid = threadIdx.x;

    if (bx < 4096) {
        size_t i = ((size_t)bx * 256 + tid) * 8;
        float4 a = *(const float4*)&x[i];
        float4 b = *(const float4*)&x[i + 4];
        union { __bf16 h[8]; uint4 u; } pk;
        pk.h[0] = (__bf16)a.x; pk.h[1] = (__bf16)a.y; pk.h[2] = (__bf16)a.z; pk.h[3] = (__bf16)a.w;
        pk.h[4] = (__bf16)b.x; pk.h[5] = (__bf16)b.y; pk.h[6] = (__bf16)b.z; pk.h[7] = (__bf16)b.w;
        *(uint4*)&xb[i] = pk.u;
        return;
    }

    const float* src;
    int ncols, c0, dr0, k0;
    if (bx < 10240) {
        int r  = bx - 4096;
        int ct = r % 96;
        k0 = (r / 96) * 32;
        if (ct < 64)      { src = Wq; ncols = 2048; c0 = ct * 32;        dr0 = ct * 32; }
        else if (ct < 80) { src = Wk; ncols = 512;  c0 = (ct - 64) * 32; dr0 = KOFF + (ct - 64) * 32; }
        else              { src = Wv; ncols = 512;  c0 = (ct - 80) * 32; dr0 = VOFF + (ct - 80) * 32; }
    } else {
        int r  = bx - 10240;
        src = Wp; ncols = 2048;
        c0  = (r & 63) * 32; dr0 = c0;
        k0  = (r >> 6) * 32;
    }
    __bf16* dst = (bx < 10240) ? wqkvT : wpT;

    int rr = tid >> 3;
    int c4 = (tid & 7) * 4;
    float4 v = *(const float4*)&src[(size_t)(k0 + rr) * ncols + c0 + c4];
    tl[rr][c4] = v.x; tl[rr][c4 + 1] = v.y; tl[rr][c4 + 2] = v.z; tl[rr][c4 + 3] = v.w;
    __syncthreads();
    union { __bf16 h[4]; uint2 u; } pk;
#pragma unroll
    for (int j = 0; j < 4; ++j) pk.h[j] = (__bf16)tl[c4 + j][rr];
    *(uint2*)&dst[(size_t)(dr0 + rr) * 2048 + k0 + c4] = pk.u;
}

// ---------------------------------------------------------------------------
// 256x256 bf16 MFMA GEMM v13: fine-interleaved phase schedule (m201-style).
//
// R10 post-mortem: dedup'd coarse bursts (24 reads then 64 MFMA, vmcnt(8)
// 2-deep) = 74.7us / MfmaUtil 27% — exactly m196's "coarse phase-split
// without fine interleave HURTS". v13 ports the verified fine structure:
//   - BK=32, FOUR LDS buffers (4 x 16KB x 2 = 128KB), staging 3 K-tiles
//     ahead -> per-tile entry s_waitcnt vmcnt(8) (2 newest tiles ride
//     through every barrier; never drains except the tail).
//     Correctness: each wave's vmcnt covers its OWN loads (FIFO); the
//     entry s_barrier then publishes all waves' loads to everyone.
//   - 2 phases per K-tile, each {4 A-frag + 4 B-frag ds_read_b128 ->
//     issue 2 staging loads of tile kt+3 -> s_barrier -> lgkmcnt(0) ->
//     setprio(1) 16 MFMA setprio(0)}. Small alternating bursts let the
//     2 waves/SIMD skew so MFMA covers the other wave's LDS reads.
//   - XOR chunk swizzle phys = chunk ^ ((row ^ row>>2) & 3) on BOTH the
//     pre-swizzled global staging source and the ds_read (involution).
//   - 8 waves (2M x 4N), wave owns 128x64 C, acc[8][4] f32x4.
// Requires K % 128 == 0 (NK multiple of 4).
// ---------------------------------------------------------------------------
template<typename TOUT>
__global__ __launch_bounds__(512, 1) void gemm256(const __bf16* __restrict__ A,
                                                  const __bf16* __restrict__ Bt,
                                                  TOUT* __restrict__ C,
                                                  int M, int N, int K, int ldc,
                                                  int nbx)
{
    __shared__ __bf16 As[4][256 * 32];
    __shared__ __bf16 Bs[4][256 * 32];

    const int tid  = threadIdx.x;
    const int wv   = tid >> 6;          // 0..7
    const int lane = tid & 63;
    const int grp  = lane >> 4;         // 0..3 (16B k-chunk within fragment)
    const int id16 = lane & 15;         // fragment row
    const int wr   = wv >> 2;           // 0..1 (M half)
    const int wc   = wv & 3;            // 0..3 (N quarter)

    // XCD-chunked bijective swizzle (grid % 8 == 0): each XCD gets a
    // contiguous chunk -> A-row-panel reuse in its private L2.
    const int nwg  = gridDim.x;
    const int cpx  = nwg >> 3;
    const int bid  = blockIdx.x;
    const int wg   = (bid & 7) * cpx + (bid >> 3);
    const int row0 = (wg / nbx) * 256;
    const int col0 = (wg % nbx) * 256;

    // ---- staging: thread covers wave-load W = wv*2+l -> rows [W*16,+16),
    //      lane: row = W*16 + (lane>>2), phys chunk = lane&3, source logical
    //      chunk c = (lane&3) ^ swz(row), swz(r) = (r ^ (r>>2)) & 3 ----
    uint soff[2];
#pragma unroll
    for (int l = 0; l < 2; ++l) {
        int r = (wv * 2 + l) * 16 + (lane >> 2);
        int c = (lane & 3) ^ ((r ^ (r >> 2)) & 3);
        soff[l] = (uint)(r * (K * 2) + c * 16);
    }
    const char* gA = (const char*)(A  + (size_t)row0 * K);
    const char* gB = (const char*)(Bt + (size_t)col0 * K);

    // ---- ds_read byte offsets (tile-invariant): row*64 + (grp^swz(row))*16 ----
    uint aoff[8], boff[4];
#pragma unroll
    for (int mf = 0; mf < 8; ++mf) {
        int r = wr * 128 + mf * 16 + id16;
        aoff[mf] = (uint)(r * 64 + ((grp ^ ((r ^ (r >> 2)) & 3)) << 4));
    }
#pragma unroll
    for (int nf = 0; nf < 4; ++nf) {
        int r = wc * 64 + nf * 16 + id16;
        boff[nf] = (uint)(r * 64 + ((grp ^ ((r ^ (r >> 2)) & 3)) << 4));
    }

    f32x4 acc[8][4];
    const f32x4 fz = {0.f, 0.f, 0.f, 0.f};
#pragma unroll
    for (int i = 0; i < 8; ++i)
#pragma unroll
        for (int j = 0; j < 4; ++j) acc[i][j] = fz;

    const int NK = K >> 5;              // 32-wide K-tiles

    // stage one (A,B) wave-load pair of tile KT into buffer BUF
#define STG(BUF, KT, L)                                                        \
    {                                                                          \
        gload_lds16(gA + (size_t)(KT) * 64 + soff[L], &As[BUF][(wv * 2 + (L)) * 512]); \
        gload_lds16(gB + (size_t)(KT) * 64 + soff[L], &Bs[BUF][(wv * 2 + (L)) * 512]); \
    }

#define TILE32(KT, BUF)                                                        \
    {                                                                          \
        if ((KT) + 3 <= NK)      { asm volatile("s_waitcnt vmcnt(8)" ::: "memory"); } \
        else if ((KT) + 2 == NK) { asm volatile("s_waitcnt vmcnt(4)" ::: "memory"); } \
        else                     { asm volatile("s_waitcnt vmcnt(0)" ::: "memory"); } \
        __builtin_amdgcn_s_barrier();                                          \
        const char* Ab = (const char*)&As[BUF][0];                             \
        const char* Bb = (const char*)&Bs[BUF][0];                             \
        _Pragma("unroll")                                                      \
        for (int p = 0; p < 2; ++p) {                                          \
            bf16x8 af[4], bfv[4];                                              \
            _Pragma("unroll")                                                  \
            for (int s = 0; s < 4; ++s)                                        \
                af[s] = *(const bf16x8*)(Ab + aoff[p * 4 + s]);                \
            _Pragma("unroll")                                                  \
            for (int n = 0; n < 4; ++n)                                        \
                bfv[n] = *(const bf16x8*)(Bb + boff[n]);                       \
            if ((KT) + 3 < NK) { STG((((BUF) + 3) & 3), (KT) + 3, p) }         \
            __builtin_amdgcn_s_barrier();                                      \
            asm volatile("s_waitcnt lgkmcnt(0)" ::: "memory");                 \
            __builtin_amdgcn_s_setprio(1);                                     \
            _Pragma("unroll")                                                  \
            for (int s = 0; s < 4; ++s)                                        \
                _Pragma("unroll")                                              \
                for (int n = 0; n < 4; ++n)                                    \
                    acc[p * 4 + s][n] =                                        \
                        __builtin_amdgcn_mfma_f32_16x16x32_bf16(af[s], bfv[n], \
                                                                acc[p * 4 + s][n], 0, 0, 0); \
            __builtin_amdgcn_s_setprio(0);                                     \
        }                                                                      \
    }

    // prologue: stage tiles 0,1,2 (FIFO tile-major; 12 loads/thread)
#pragma unroll
    for (int t = 0; t < 3; ++t) {
        STG(t, t, 0)
        STG(t, t, 1)
    }

    for (int kt = 0; kt < NK; kt += 4) {
        TILE32(kt,     0);
        TILE32(kt + 1, 1);
        TILE32(kt + 2, 2);
        TILE32(kt + 3, 3);
    }

    // epilogue
#pragma unroll
    for (int mf = 0; mf < 8; ++mf) {
        int gr = row0 + wr * 128 + mf * 16 + grp * 4;
#pragma unroll
        for (int nf = 0; nf < 4; ++nf) {
            int gc = col0 + wc * 64 + nf * 16 + id16;
#pragma unroll
            for (int r = 0; r < 4; ++r) {
                if constexpr (sizeof(TOUT) == 4)
                    C[(size_t)(gr + r) * ldc + gc] = acc[mf][nf][r];
                else
                    C[(size_t)(gr + r) * ldc + gc] = (TOUT)acc[mf][nf][r];
            }
        }
    }
#undef TILE32
#undef STG
}

// ---------------------------------------------------------------------------
// bf16 MFMA GEMM, single-barrier double-buffered: C = A(MxK) @ Bt^T, Bt [N,K].
// 128x128 tile, BK=32, 4 waves. (kept for the out-projection: N=2048 gives
// only 128 blocks at 256^2 = half the machine idle)
// ---------------------------------------------------------------------------
template<typename TOUT>
__global__ __launch_bounds__(256) void gemm_bt(const __bf16* __restrict__ A,
                                               const __bf16* __restrict__ Bt,
                                               TOUT* __restrict__ C,
                                               int M, int N, int K, int ldc)
{
    __shared__ __bf16 As[2][128 * 32];   // [m][k]
    __shared__ __bf16 Bs[2][128 * 32];   // [n][k]

    const int tid  = threadIdx.x;
    const int wv   = tid >> 6;
    const int lane = tid & 63;
    const int grp  = lane >> 4;
    const int id16 = lane & 15;
    const int wr   = wv >> 1;
    const int wc   = wv & 1;

    const int row0 = blockIdx.y * 128;
    const int col0 = blockIdx.x * 128;

    const int sm = tid >> 2;
    const int sk = (tid & 3) << 3;

    const __bf16* ga0 = A  + (size_t)(row0 + sm) * K + sk;
    const __bf16* ga1 = A  + (size_t)(row0 + 64 + sm) * K + sk;
    const __bf16* gb0 = Bt + (size_t)(col0 + sm) * K + sk;
    const __bf16* gb1 = Bt + (size_t)(col0 + 64 + sm) * K + sk;

    f32x4 acc[4][4];
    const f32x4 fz = {0.f, 0.f, 0.f, 0.f};
#pragma unroll
    for (int i = 0; i < 4; ++i)
#pragma unroll
        for (int j = 0; j < 4; ++j) acc[i][j] = fz;

    const int nk = K >> 5;

    {
        __bf16* a0 = &As[0][wv << 9];
        __bf16* b0 = &Bs[0][wv << 9];
        gload_lds16(ga0, a0);
        gload_lds16(ga1, a0 + 2048);
        gload_lds16(gb0, b0);
        gload_lds16(gb1, b0 + 2048);
    }

    for (int kt = 0; kt < nk; ++kt) {
        const int bufc = kt & 1;
        asm volatile("s_waitcnt vmcnt(0)" ::: "memory");
        __syncthreads();

        if (kt + 1 < nk) {
            const int kb = (kt + 1) << 5;
            __bf16* a0 = &As[1 - bufc][wv << 9];
            __bf16* b0 = &Bs[1 - bufc][wv << 9];
            gload_lds16(ga0 + kb, a0);
            gload_lds16(ga1 + kb, a0 + 2048);
            gload_lds16(gb0 + kb, b0);
            gload_lds16(gb1 + kb, b0 + 2048);
        }

        bf16x8 af[4], bfr[4];
#pragma unroll
        for (int i = 0; i < 4; ++i)
            af[i] = *(const bf16x8*)&As[bufc][((wr << 6) + (i << 4) + id16) * 32 + (grp << 3)];
#pragma unroll
        for (int j = 0; j < 4; ++j)
            bfr[j] = *(const bf16x8*)&Bs[bufc][((wc << 6) + (j << 4) + id16) * 32 + (grp << 3)];
#pragma unroll
        for (int i = 0; i < 4; ++i)
#pragma unroll
            for (int j = 0; j < 4; ++j)
                acc[i][j] = __builtin_amdgcn_mfma_f32_16x16x32_bf16(af[i], bfr[j], acc[i][j], 0, 0, 0);
    }

#pragma unroll
    for (int i = 0; i < 4; ++i) {
        int gr = row0 + (wr << 6) + (i << 4) + (grp << 2);
#pragma unroll
        for (int j = 0; j < 4; ++j) {
            int gc = col0 + (wc << 6) + (j << 4) + id16;
#pragma unroll
            for (int r = 0; r < 4; ++r) {
                if constexpr (sizeof(TOUT) == 4)
                    C[(size_t)(gr + r) * ldc + gc] = acc[i][j][r];
                else
                    C[(size_t)(gr + r) * ldc + gc] = (TOUT)acc[i][j][r];
            }
        }
    }
}

// ---------------------------------------------------------------------------
// rope_vt: RoPE+RMSNorm for q AND k + V transpose.
// ---------------------------------------------------------------------------
__global__ __launch_bounds__(256) void rope_vt(__bf16* __restrict__ qkv,
                                               const float* __restrict__ cosb,
                                               const float* __restrict__ sinb,
                                               __bf16* __restrict__ vt)
{
    __shared__ __bf16 tl[32][HD_ + 8];
    const int bx  = blockIdx.x;
    const int tid = threadIdx.x;

    if (bx < 20480) {
        int gw   = bx * 4 + (tid >> 6);
        int lane = tid & 63;
        int bt = gw / 20;
        int hd = gw % 20;
        int t  = bt & (T_ - 1);
        float scale = (hd < 16) ? QSCALE : 1.0f;

        __bf16* p = qkv + (size_t)bt * QKVLD + hd * HD_;
        float c = cosb[t * 64 + lane];
        float s = sinb[t * 64 + lane];
        float x1 = (float)p[lane];
        float x2 = (float)p[lane + 64];
        float r1 = x1 * c - x2 * s;
        float r2 = x1 * s + x2 * c;
        float ss = r1 * r1 + r2 * r2;
#pragma unroll
        for (int off = 32; off; off >>= 1) ss += __shfl_xor(ss, off, 64);
        float inv = rsqrtf(ss * (1.f / 128.f) + 1e-6f) * scale;
        p[lane]      = (__bf16)(r1 * inv);
        p[lane + 64] = (__bf16)(r2 * inv);
        return;
    }
    {
        int vbx = bx - 20480;
        int st  = vbx & 63;
        int bkv = vbx >> 6;
        int b = bkv >> 2, kv = bkv & 3;
        int s0 = st << 5;
        {
            int s = tid >> 3;
            int d = (tid & 7) << 4;
            const __bf16* src = qkv + (size_t)(b * T_ + s0 + s) * QKVLD + VOFF + kv * HD_ + d;
            *(bf16x8*)&tl[s][d]     = *(const bf16x8*)src;
            *(bf16x8*)&tl[s][d + 8] = *(const bf16x8*)(src + 8);
        }
        __syncthreads();
        {
            int d  = tid >> 1;
            int sh = (tid & 1) << 4;
            __bf16 tmp[16];
#pragma unroll
            for (int j = 0; j < 16; ++j) tmp[j] = tl[sh + j][d];
            __bf16* dst = vt + ((size_t)(b * NKV_ + kv) * HD_ + d) * T_ + s0 + sh;
            *(bf16x8*)dst       = *(bf16x8*)&tmp[0];
            *(bf16x8*)(dst + 8) = *(bf16x8*)&tmp[8];
        }
    }
}

// ---------------------------------------------------------------------------
// Flash attention v10 (unchanged from R8 best): uniform 17-tile A/B blocks,
// KVBLK=64, 32x32 MFMA, in-register softmax, permlane32_swap half-exchange,
// fast exp2, hoisted LDS offsets, XCD clustering, separate combine kernel.
// ---------------------------------------------------------------------------
__global__ __launch_bounds__(256, 2) void attn32(const __bf16* __restrict__ qkv,
                                                 const __bf16* __restrict__ vbT,
                                                 __bf16* __restrict__ y,
                                                 float* __restrict__ pOA,
                                                 float* __restrict__ pOB,
                                                 float* __restrict__ pLA,
                                                 float* __restrict__ pLB)
{
    __shared__ __bf16 Ks[2][64 * 128];   // [key][d] , chunk16 ^ (row&15)
    __shared__ __bf16 Vs[2][64 * 128];   // row r: d=r keys0..63 | d=r+64 keys0..63

    const int tid  = threadIdx.x;
    const int wv   = tid >> 6;
    const int lane = tid & 63;
    const int l31  = lane & 31;
    const int h32  = lane >> 5;

    // XCD-clustered decode: cluster (b,kv) = bx&7; member = bx>>3.
    const int bx   = blockIdx.x;         // 512
    const int b    = (bx >> 2) & 1;
    const int kv   = bx & 3;
    const int m    = bx >> 3;            // 0..63
    const int hh   = m & 3;
    const int role = (m >> 2) & 1;       // 0 = A (hi prefix), 1 = B (hi rest + lo)
    const int p    = m >> 3;             // 0..7
    const int h    = kv * 4 + hh;
    const int bh   = b * 16 + h;
    const int slot = p * 32 + bh;

    const int hi  = 15 - p;              // 8..15
    const int lo  = p;                   // 0..7
    const int tts = role ? (15 - 2 * p) : 99;   // B's phase switch (1..15)

    auto KT = [&](int t) { return role ? (t < tts ? 17 + t : t - tts) : t; };

    int qw0 = hi * 128 + wv * 32;        // wave's first q row (phase 0)
    int qme = qw0 + l31;

    uint koff[4], voff[4];
#pragma unroll
    for (int i = 0; i < 4; ++i) {
        int r  = (wv * 4 + i) * 4 + (lane >> 4);   // LDS row 0..63
        int c  = lane & 15;                        // physical 16B chunk
        int cs = c ^ (r & 15);                     // logical chunk at source
        koff[i] = (uint)(r * (QKVLD * 2) + cs * 16);           // K[key=r][d=cs*8]
        int d   = r + ((cs >> 3) << 6);                        // V^T row packing
        voff[i] = (uint)(d * (T_ * 2) + (cs & 7) * 16);        // V^T[d][t=(cs&7)*8]
    }
    const char* kg = (const char*)(qkv + (size_t)b * T_ * QKVLD + KOFF + kv * HD_);
    const char* vg = (const char*)(vbT + ((size_t)(b * NKV_ + kv) * HD_) * T_);

    uint off8[8];
#pragma unroll
    for (int s = 0; s < 8; ++s)
        off8[s] = (uint)(l31 * 256 + ((((s << 1) + h32) ^ (l31 & 15)) << 4));

#define STAGE(BUF, KN)                                                        \
    {                                                                         \
        const char* kp = kg + (size_t)(KN) * (64 * QKVLD * 2);                \
        const char* vp = vg + (size_t)(KN) * (64 * 2);                        \
        __bf16* kl = &Ks[BUF][(wv * 4) * 512];                                \
        __bf16* vl = &Vs[BUF][(wv * 4) * 512];                                \
        _Pragma("unroll")                                                     \
        for (int i = 0; i < 4; ++i) gload_lds16(kp + koff[i], kl + i * 512);  \
        _Pragma("unroll")                                                     \
        for (int i = 0; i < 4; ++i) gload_lds16(vp + voff[i], vl + i * 512);  \
    }

    bf16x8 qf[8], qf2[8];
    {
        const __bf16* qp = qkv + (size_t)(b * T_ + hi * 128 + wv * 32 + l31) * QKVLD + h * HD_ + h32 * 8;
#pragma unroll
        for (int s = 0; s < 8; ++s) qf[s] = *(const bf16x8*)(qp + s * 16);
        const __bf16* qp2 = qkv + (size_t)(b * T_ + lo * 128 + wv * 32 + l31) * QKVLD + h * HD_ + h32 * 8;
#pragma unroll
        for (int s = 0; s < 8; ++s) qf2[s] = *(const bf16x8*)(qp2 + s * 16);
    }

    f32x16 o[4];
#pragma unroll
    for (int dt = 0; dt < 4; ++dt)
#pragma unroll
        for (int r = 0; r < 16; ++r) o[dt][r] = 0.f;
    float l_p = 0.f;

#define STORE_PARTIAL(PO, PL)                                                   \
    {                                                                           \
        float lsum = l_p + __shfl_xor(l_p, 32, 64);                             \
        int qloc = wv * 32 + l31;                                               \
        float* po = (PO) + ((size_t)slot * 128 + qloc) * 128;                   \
        _Pragma("unroll")                                                       \
        for (int dt = 0; dt < 4; ++dt)                                          \
            _Pragma("unroll")                                                   \
            for (int g = 0; g < 4; ++g) {                                       \
                float4 f = {o[dt][4 * g + 0], o[dt][4 * g + 1],                 \
                            o[dt][4 * g + 2], o[dt][4 * g + 3]};                \
                *(float4*)&po[dt * 32 + 8 * g + 4 * h32] = f;                   \
            }                                                                   \
        if (h32 == 0) (PL)[slot * 128 + qloc] = lsum;                           \
    }

#define TILE_BODY(TT, BUFC)                                                     \
    {                                                                           \
        const int tt_ = (TT);                                                   \
        asm volatile("s_waitcnt vmcnt(0)" ::: "memory");                        \
        __syncthreads();                                                        \
        if (tt_ + 1 < 17) { int kn_ = KT(tt_ + 1); STAGE(1 - (BUFC), kn_); }    \
        if (role && tt_ == tts) {                                               \
            STORE_PARTIAL(pOB, pLB);                                            \
            _Pragma("unroll")                                                   \
            for (int dt = 0; dt < 4; ++dt)                                      \
                _Pragma("unroll")                                               \
                for (int r = 0; r < 16; ++r) o[dt][r] = 0.f;                    \
            l_p = 0.f;                                                          \
            _Pragma("unroll")                                                   \
            for (int s = 0; s < 8; ++s) qf[s] = qf2[s];                         \
            qw0 = lo * 128 + wv * 32;                                           \
            qme = qw0 + l31;                                                    \
        }                                                                       \
        const int s0 = KT(tt_) << 6;                                            \
        if (s0 <= qw0 + 31) {                                                   \
            const char* Kb = (const char*)&Ks[BUFC][0];                         \
            const char* Vb = (const char*)&Vs[BUFC][0];                         \
            f32x16 S0, S1;                                                      \
            _Pragma("unroll")                                                   \
            for (int r = 0; r < 16; ++r) { S0[r] = 0.f; S1[r] = 0.f; }          \
            __builtin_amdgcn_s_setprio(1);                                      \
            _Pragma("unroll")                                                   \
            for (int s = 0; s < 8; ++s) {                                       \
                bf16x8 kf0 = *(const bf16x8*)(Kb + off8[s]);                    \
                bf16x8 kf1 = *(const bf16x8*)(Kb + off8[s] + 8192);             \
                S0 = __builtin_amdgcn_mfma_f32_32x32x16_bf16(kf0, qf[s], S0, 0, 0, 0); \
                S1 = __builtin_amdgcn_mfma_f32_32x32x16_bf16(kf1, qf[s], S1, 0, 0, 0); \
            }                                                                   \
            __builtin_amdgcn_s_setprio(0);                                      \
            const bool domask = (s0 + 63 > qw0);                                \
            uint w[16];                                                         \
            _Pragma("unroll")                                                   \
            for (int i = 0; i < 8; ++i) {                                       \
                const int r0 = 2 * i;                                           \
                float e0 = EXP2F(S0[r0]);                                       \
                float e1 = EXP2F(S0[r0 + 1]);                                   \
                if (domask) {                                                   \
                    int k0 = s0 + (r0 & 3) + 8 * (r0 >> 2) + 4 * h32;           \
                    if (k0     > qme) e0 = 0.f;                                 \
                    if (k0 + 1 > qme) e1 = 0.f;                                 \
                }                                                               \
                l_p += e0 + e1;                                                 \
                union { __bf16 h2[2]; uint u; } pk;                             \
                pk.h2[0] = (__bf16)e0; pk.h2[1] = (__bf16)e1;                   \
                w[i] = pk.u;                                                    \
            }                                                                   \
            _Pragma("unroll")                                                   \
            for (int i = 0; i < 8; ++i) {                                       \
                const int r0 = 2 * i;                                           \
                float e0 = EXP2F(S1[r0]);                                       \
                float e1 = EXP2F(S1[r0 + 1]);                                   \
                if (domask) {                                                   \
                    int k0 = s0 + 32 + (r0 & 3) + 8 * (r0 >> 2) + 4 * h32;      \
                    if (k0     > qme) e0 = 0.f;                                 \
                    if (k0 + 1 > qme) e1 = 0.f;                                 \
                }                                                               \
                l_p += e0 + e1;                                                 \
                union { __bf16 h2[2]; uint u; } pk;                             \
                pk.h2[0] = (__bf16)e0; pk.h2[1] = (__bf16)e1;                   \
                w[8 + i] = pk.u;                                                \
            }                                                                   \
            union U8 { uint u[4]; bf16x8 v; };                                  \
            bf16x8 pf[4];                                                       \
            _Pragma("unroll")                                                   \
            for (int ks = 0; ks < 4; ++ks) {                                    \
                const int bsel = ((ks >> 1) << 3) + ((ks & 1) << 2);            \
                uint a0 = w[bsel],     b0 = w[bsel + 2];                        \
                uint a1 = w[bsel + 1], b1 = w[bsel + 3];                        \
                asm("v_permlane32_swap_b32 %0, %1" : "+v"(a0), "+v"(b0));       \
                asm("v_permlane32_swap_b32 %0, %1" : "+v"(a1), "+v"(b1));       \
                U8 t;                                                           \
                t.u[0] = a0; t.u[1] = a1; t.u[2] = b0; t.u[3] = b1;             \
                pf[ks] = t.v;                                                   \
            }                                                                   \
            __builtin_amdgcn_s_setprio(1);                                      \
            _Pragma("unroll")                                                   \
            for (int dt = 0; dt < 4; ++dt) {                                    \
                const int ab = (dt >> 1) << 2;                                  \
                const int hf = (dt & 1) * 8192;                                 \
                _Pragma("unroll")                                               \
                for (int ks = 0; ks < 4; ++ks) {                                \
                    bf16x8 vf = *(const bf16x8*)(Vb + off8[ab + ks] + hf);      \
                    o[dt] = __builtin_amdgcn_mfma_f32_32x32x16_bf16(vf, pf[ks], o[dt], 0, 0, 0); \
                }                                                               \
            }                                                                   \
            __builtin_amdgcn_s_setprio(0);                                      \
        }                                                                       \
    }

    STAGE(0, KT(0));

    for (int tt = 0; tt < 16; tt += 2) {
        TILE_BODY(tt, 0);
        TILE_BODY(tt + 1, 1);
    }
    TILE_BODY(16, 0);

    if (role == 0) {
        STORE_PARTIAL(pOA, pLA);
    } else {
        float l  = l_p + __shfl_xor(l_p, 32, 64);
        float inv = 1.f / l;
        __bf16* yp = y + (size_t)(b * T_ + qw0 + l31) * C_ + h * HD_;
#pragma unroll
        for (int dt = 0; dt < 4; ++dt)
#pragma unroll
            for (int g = 0; g < 4; ++g) {
                union { __bf16 h4[4]; uint2 u; } pk;
#pragma unroll
                for (int e = 0; e < 4; ++e) pk.h4[e] = (__bf16)(o[dt][4 * g + e] * inv);
                *(uint2*)&yp[dt * 32 + 8 * g + 4 * h32] = pk.u;
            }
    }
#undef TILE_BODY
#undef STORE_PARTIAL
#undef STAGE
}

// ---------------------------------------------------------------------------
// Combine hi-tile partials: y = (oA + oB) / (lA + lB).  256 blocks x 256 thr.
// ---------------------------------------------------------------------------
__global__ __launch_bounds__(256) void attn_combine(const float* __restrict__ pOA,
                                                    const float* __restrict__ pOB,
                                                    const float* __restrict__ pLA,
                                                    const float* __restrict__ pLB,
                                                    __bf16* __restrict__ y)
{
    int slot = blockIdx.x;               // p*32 + bh
    int p  = slot >> 5, bh = slot & 31;
    int b  = bh >> 4,   h  = bh & 15;
    int hi = 15 - p;
    int t  = threadIdx.x;
    int q  = t >> 1;                     // 0..127
    int dh = (t & 1) << 6;               // 0 or 64

    float inv = 1.f / (pLA[slot * 128 + q] + pLB[slot * 128 + q]);
    size_t base = ((size_t)slot * 128 + q) * 128 + dh;
    __bf16* yp = y + (size_t)(b * T_ + hi * 128 + q) * C_ + h * HD_ + dh;
#pragma unroll
    for (int d0 = 0; d0 < 64; d0 += 8) {
        float4 a0 = *(const float4*)&pOA[base + d0];
        float4 a1 = *(const float4*)&pOA[base + d0 + 4];
        float4 b0 = *(const float4*)&pOB[base + d0];
        float4 b1 = *(const float4*)&pOB[base + d0 + 4];
        union { __bf16 h8[8]; uint4 u; } pk;
        pk.h8[0] = (__bf16)((a0.x + b0.x) * inv);
        pk.h8[1] = (__bf16)((a0.y + b0.y) * inv);
        pk.h8[2] = (__bf16)((a0.z + b0.z) * inv);
        pk.h8[3] = (__bf16)((a0.w + b0.w) * inv);
        pk.h8[4] = (__bf16)((a1.x + b1.x) * inv);
        pk.h8[5] = (__bf16)((a1.y + b1.y) * inv);
        pk.h8[6] = (__bf16)((a1.z + b1.z) * inv);
        pk.h8[7] = (__bf16)((a1.w + b1.w) * inv);
        *(uint4*)&yp[d0] = pk.u;
    }
}

// ---------------------------------------------------------------------------
extern "C" void kernel_launch(void* const* d_in, const int* in_sizes, int n_in,
                              void* d_out, int out_size, void* d_ws, size_t ws_size,
                              hipStream_t stream)
{
    const float* x    = (const float*)d_in[0];
    const float* cosb = (const float*)d_in[1];
    const float* sinb = (const float*)d_in[2];
    const float* Wq   = (const float*)d_in[3];
    const float* Wk   = (const float*)d_in[4];
    const float* Wv   = (const float*)d_in[5];
    const float* Wp   = (const float*)d_in[6];
    float* out = (float*)d_out;

    const int M = B_ * T_;   // 4096

    // workspace: xb | qkv | wqkvT | wpT | vt | y | pOB   (~101 MB)
    // pOA aliases xb (dead after gemm1); pL* alias wqkvT.
    char* w = (char*)d_ws;
    __bf16* xb    = (__bf16*)w;  w += (size_t)M * C_ * 2;
    __bf16* qkv   = (__bf16*)w;  w += (size_t)M * QKVLD * 2;
    __bf16* wqkvT = (__bf16*)w;  w += (size_t)QKVLD * C_ * 2;
    __bf16* wpT   = (__bf16*)w;  w += (size_t)C_ * C_ * 2;
    __bf16* vt    = (__bf16*)w;  w += (size_t)M * NKV_ * HD_ * 2;
    __bf16* y     = (__bf16*)w;  w += (size_t)M * C_ * 2;
    float*  pOB   = (float*)w;
    float*  pOA   = (float*)xb;
    float*  pLA   = (float*)wqkvT;
    float*  pLB   = pLA + 8 * 32 * 128;

    // fused preprocessing (cast + both weight transposes): 1 launch
    prep<<<14336, 256, 0, stream>>>(x, Wq, Wk, Wv, Wp, xb, wqkvT, wpT);

    // fused QKV projection: fine-interleaved 256^2 GEMM (192 blocks, 12 N-tiles)
    gemm256<__bf16><<<192, 512, 0, stream>>>(xb, wqkvT, qkv, M, QKVLD, C_, QKVLD, QKVLD / 256);

    // RoPE+RMSNorm (q+k) + V transpose: 1 launch
    rope_vt<<<20992, 256, 0, stream>>>(qkv, cosb, sinb, vt);

    // flash attention v10 + separate combine
    attn32<<<512, 256, 0, stream>>>(qkv, vt, y, pOA, pOB, pLA, pLB);
    attn_combine<<<256, 256, 0, stream>>>(pOA, pOB, pLA, pLB, y);

    // output projection (bf16 MFMA, fp32 out, dbuf, 128^2: grid 512)
    gemm_bt<float><<<dim3(C_ / 128, M / 128), 256, 0, stream>>>(y, wpT, out, M, C_, C_, C_);
}

// Round 12
// 306.307 us; speedup vs baseline: 1.0209x; 1.0209x over previous
//
#include <hip/hip_runtime.h>
#include <hip/hip_bf16.h>
#include <math.h>

// Problem constants (CausalSelfAttention_84928683311105)
#define B_  2
#define T_  2048
#define C_  2048
#define NH_ 16
#define NKV_ 4
#define HD_ 128
#define NREP_ (NH_/NKV_)     // 4

// fused QKV output layout: [B*T, 3072] ; q @ 0, k @ 2048, v @ 2560
#define QKVLD 3072
#define KOFF  2048
#define VOFF  2560

// q scale: (1/sqrt(d))^2 folded = 1/128, times log2(e) so scores are in
// log2 units and softmax exp is a single native v_exp_f32.
#define QSCALE 0.01127105500694502f

// fast exp2: bare v_exp_f32 when the builtin exists (libm exp2f adds guards)
#if defined(__has_builtin)
# if __has_builtin(__builtin_amdgcn_exp2f)
#  define EXP2F(x) __builtin_amdgcn_exp2f(x)
# else
#  define EXP2F(x) exp2f(x)
# endif
#else
# define EXP2F(x) exp2f(x)
#endif

typedef __bf16 bf16x8 __attribute__((ext_vector_type(8)));
typedef float  f32x4  __attribute__((ext_vector_type(4)));
typedef float  f32x16 __attribute__((ext_vector_type(16)));

__device__ inline void gload_lds16(const void* g, void* l) {
    __builtin_amdgcn_global_load_lds((const __attribute__((address_space(1))) void*)g,
                                     (__attribute__((address_space(3))) void*)l, 16, 0, 0);
}

// ---------------------------------------------------------------------------
// prep: cast_bf16 + wtrans_qkv + wtrans(Wp) fused into one launch.
// ---------------------------------------------------------------------------
__global__ __launch_bounds__(256) void prep(const float* __restrict__ x,
                                            const float* __restrict__ Wq,
                                            const float* __restrict__ Wk,
                                            const float* __restrict__ Wv,
                                            const float* __restrict__ Wp,
                                            __bf16* __restrict__ xb,
                                            __bf16* __restrict__ wqkvT,
                                            __bf16* __restrict__ wpT)
{
    __shared__ float tl[32][33];
    const int bx  = blockIdx.x;
    const int tid = threadIdx.x;

    if (bx < 4096) {
        size_t i = ((size_t)bx * 256 + tid) * 8;
        float4 a = *(const float4*)&x[i];
        float4 b = *(const float4*)&x[i + 4];
        union { __bf16 h[8]; uint4 u; } pk;
        pk.h[0] = (__bf16)a.x; pk.h[1] = (__bf16)a.y; pk.h[2] = (__bf16)a.z; pk.h[3] = (__bf16)a.w;
        pk.h[4] = (__bf16)b.x; pk.h[5] = (__bf16)b.y; pk.h[6] = (__bf16)b.z; pk.h[7] = (__bf16)b.w;
        *(uint4*)&xb[i] = pk.u;
        return;
    }

    const float* src;
    int ncols, c0, dr0, k0;
    if (bx < 10240) {
        int r  = bx - 4096;
        int ct = r % 96;
        k0 = (r / 96) * 32;
        if (ct < 64)      { src = Wq; ncols = 2048; c0 = ct * 32;        dr0 = ct * 32; }
        else if (ct < 80) { src = Wk; ncols = 512;  c0 = (ct - 64) * 32; dr0 = KOFF + (ct - 64) * 32; }
        else              { src = Wv; ncols = 512;  c0 = (ct - 80) * 32; dr0 = VOFF + (ct - 80) * 32; }
    } else {
        int r  = bx - 10240;
        src = Wp; ncols = 2048;
        c0  = (r & 63) * 32; dr0 = c0;
        k0  = (r >> 6) * 32;
    }
    __bf16* dst = (bx < 10240) ? wqkvT : wpT;

    int rr = tid >> 3;
    int c4 = (tid & 7) * 4;
    float4 v = *(const float4*)&src[(size_t)(k0 + rr) * ncols + c0 + c4];
    tl[rr][c4] = v.x; tl[rr][c4 + 1] = v.y; tl[rr][c4 + 2] = v.z; tl[rr][c4 + 3] = v.w;
    __syncthreads();
    union { __bf16 h[4]; uint2 u; } pk;
#pragma unroll
    for (int j = 0; j < 4; ++j) pk.h[j] = (__bf16)tl[c4 + j][rr];
    *(uint2*)&dst[(size_t)(dr0 + rr) * 2048 + k0 + c4] = pk.u;
}

// ---------------------------------------------------------------------------
// bf16 MFMA GEMM, single-barrier double-buffered: C = A(MxK) @ Bt^T, Bt [N,K].
// 128x128 tile, BK=32, 4 waves, global_load_lds(16B) prefetch into alt buffer.
// v14: + XCD-chunked block swizzle (T1). Grid must satisfy (gx*gy) % 8 == 0.
// Mechanism: default linear block->XCD round-robin makes all 8 private L2s
// re-pull the same B panel (QKV FETCH 71.7MB vs ~29MB unique). Chunking gives
// each XCD a contiguous row-band -> A panel resident in its 4MB L2.
// ---------------------------------------------------------------------------
template<typename TOUT>
__global__ __launch_bounds__(256) void gemm_bt(const __bf16* __restrict__ A,
                                               const __bf16* __restrict__ Bt,
                                               TOUT* __restrict__ C,
                                               int M, int N, int K, int ldc)
{
    __shared__ __bf16 As[2][128 * 32];   // [m][k]
    __shared__ __bf16 Bs[2][128 * 32];   // [n][k]

    const int tid  = threadIdx.x;
    const int wv   = tid >> 6;
    const int lane = tid & 63;
    const int grp  = lane >> 4;
    const int id16 = lane & 15;
    const int wr   = wv >> 1;
    const int wc   = wv & 1;

    // XCD-chunked bijective swizzle of the flattened block id
    const int gx  = gridDim.x;
    const int nwg = gx * gridDim.y;
    const int q8  = nwg >> 3;
    const int lid = blockIdx.x + gx * blockIdx.y;
    const int swz = (lid & 7) * q8 + (lid >> 3);
    const int row0 = (swz / gx) * 128;
    const int col0 = (swz % gx) * 128;

    const int sm = tid >> 2;
    const int sk = (tid & 3) << 3;

    const __bf16* ga0 = A  + (size_t)(row0 + sm) * K + sk;
    const __bf16* ga1 = A  + (size_t)(row0 + 64 + sm) * K + sk;
    const __bf16* gb0 = Bt + (size_t)(col0 + sm) * K + sk;
    const __bf16* gb1 = Bt + (size_t)(col0 + 64 + sm) * K + sk;

    f32x4 acc[4][4];
    const f32x4 fz = {0.f, 0.f, 0.f, 0.f};
#pragma unroll
    for (int i = 0; i < 4; ++i)
#pragma unroll
        for (int j = 0; j < 4; ++j) acc[i][j] = fz;

    const int nk = K >> 5;

    // prologue: stage tile 0 into buf 0
    {
        __bf16* a0 = &As[0][wv << 9];
        __bf16* b0 = &Bs[0][wv << 9];
        gload_lds16(ga0, a0);
        gload_lds16(ga1, a0 + 2048);
        gload_lds16(gb0, b0);
        gload_lds16(gb1, b0 + 2048);
    }

    for (int kt = 0; kt < nk; ++kt) {
        const int bufc = kt & 1;
        asm volatile("s_waitcnt vmcnt(0)" ::: "memory");
        __syncthreads();

        if (kt + 1 < nk) {
            const int kb = (kt + 1) << 5;
            __bf16* a0 = &As[1 - bufc][wv << 9];
            __bf16* b0 = &Bs[1 - bufc][wv << 9];
            gload_lds16(ga0 + kb, a0);
            gload_lds16(ga1 + kb, a0 + 2048);
            gload_lds16(gb0 + kb, b0);
            gload_lds16(gb1 + kb, b0 + 2048);
        }

        bf16x8 af[4], bfr[4];
#pragma unroll
        for (int i = 0; i < 4; ++i)
            af[i] = *(const bf16x8*)&As[bufc][((wr << 6) + (i << 4) + id16) * 32 + (grp << 3)];
#pragma unroll
        for (int j = 0; j < 4; ++j)
            bfr[j] = *(const bf16x8*)&Bs[bufc][((wc << 6) + (j << 4) + id16) * 32 + (grp << 3)];
#pragma unroll
        for (int i = 0; i < 4; ++i)
#pragma unroll
            for (int j = 0; j < 4; ++j)
                acc[i][j] = __builtin_amdgcn_mfma_f32_16x16x32_bf16(af[i], bfr[j], acc[i][j], 0, 0, 0);
    }

#pragma unroll
    for (int i = 0; i < 4; ++i) {
        int gr = row0 + (wr << 6) + (i << 4) + (grp << 2);
#pragma unroll
        for (int j = 0; j < 4; ++j) {
            int gc = col0 + (wc << 6) + (j << 4) + id16;
#pragma unroll
            for (int r = 0; r < 4; ++r) {
                if constexpr (sizeof(TOUT) == 4)
                    C[(size_t)(gr + r) * ldc + gc] = acc[i][j][r];
                else
                    C[(size_t)(gr + r) * ldc + gc] = (TOUT)acc[i][j][r];
            }
        }
    }
}

// ---------------------------------------------------------------------------
// rope_vt: RoPE+RMSNorm for q AND k + V transpose.
// ---------------------------------------------------------------------------
__global__ __launch_bounds__(256) void rope_vt(__bf16* __restrict__ qkv,
                                               const float* __restrict__ cosb,
                                               const float* __restrict__ sinb,
                                               __bf16* __restrict__ vt)
{
    __shared__ __bf16 tl[32][HD_ + 8];
    const int bx  = blockIdx.x;
    const int tid = threadIdx.x;

    if (bx < 20480) {
        int gw   = bx * 4 + (tid >> 6);
        int lane = tid & 63;
        int bt = gw / 20;
        int hd = gw % 20;
        int t  = bt & (T_ - 1);
        float scale = (hd < 16) ? QSCALE : 1.0f;

        __bf16* p = qkv + (size_t)bt * QKVLD + hd * HD_;
        float c = cosb[t * 64 + lane];
        float s = sinb[t * 64 + lane];
        float x1 = (float)p[lane];
        float x2 = (float)p[lane + 64];
        float r1 = x1 * c - x2 * s;
        float r2 = x1 * s + x2 * c;
        float ss = r1 * r1 + r2 * r2;
#pragma unroll
        for (int off = 32; off; off >>= 1) ss += __shfl_xor(ss, off, 64);
        float inv = rsqrtf(ss * (1.f / 128.f) + 1e-6f) * scale;
        p[lane]      = (__bf16)(r1 * inv);
        p[lane + 64] = (__bf16)(r2 * inv);
        return;
    }
    {
        int vbx = bx - 20480;
        int st  = vbx & 63;
        int bkv = vbx >> 6;
        int b = bkv >> 2, kv = bkv & 3;
        int s0 = st << 5;
        {
            int s = tid >> 3;
            int d = (tid & 7) << 4;
            const __bf16* src = qkv + (size_t)(b * T_ + s0 + s) * QKVLD + VOFF + kv * HD_ + d;
            *(bf16x8*)&tl[s][d]     = *(const bf16x8*)src;
            *(bf16x8*)&tl[s][d + 8] = *(const bf16x8*)(src + 8);
        }
        __syncthreads();
        {
            int d  = tid >> 1;
            int sh = (tid & 1) << 4;
            __bf16 tmp[16];
#pragma unroll
            for (int j = 0; j < 16; ++j) tmp[j] = tl[sh + j][d];
            __bf16* dst = vt + ((size_t)(b * NKV_ + kv) * HD_ + d) * T_ + s0 + sh;
            *(bf16x8*)dst       = *(bf16x8*)&tmp[0];
            *(bf16x8*)(dst + 8) = *(bf16x8*)&tmp[8];
        }
    }
}

// ---------------------------------------------------------------------------
// Flash attention v10 (unchanged from R8 best): uniform 17-tile A/B blocks,
// KVBLK=64, 32x32 MFMA, in-register softmax, permlane32_swap half-exchange,
// fast exp2, hoisted LDS offsets, XCD clustering, separate combine kernel.
// ---------------------------------------------------------------------------
__global__ __launch_bounds__(256, 2) void attn32(const __bf16* __restrict__ qkv,
                                                 const __bf16* __restrict__ vbT,
                                                 __bf16* __restrict__ y,
                                                 float* __restrict__ pOA,
                                                 float* __restrict__ pOB,
                                                 float* __restrict__ pLA,
                                                 float* __restrict__ pLB)
{
    __shared__ __bf16 Ks[2][64 * 128];   // [key][d] , chunk16 ^ (row&15)
    __shared__ __bf16 Vs[2][64 * 128];   // row r: d=r keys0..63 | d=r+64 keys0..63

    const int tid  = threadIdx.x;
    const int wv   = tid >> 6;
    const int lane = tid & 63;
    const int l31  = lane & 31;
    const int h32  = lane >> 5;

    // XCD-clustered decode: cluster (b,kv) = bx&7; member = bx>>3.
    const int bx   = blockIdx.x;         // 512
    const int b    = (bx >> 2) & 1;
    const int kv   = bx & 3;
    const int m    = bx >> 3;            // 0..63
    const int hh   = m & 3;
    const int role = (m >> 2) & 1;       // 0 = A (hi prefix), 1 = B (hi rest + lo)
    const int p    = m >> 3;             // 0..7
    const int h    = kv * 4 + hh;
    const int bh   = b * 16 + h;
    const int slot = p * 32 + bh;

    const int hi  = 15 - p;              // 8..15
    const int lo  = p;                   // 0..7
    const int tts = role ? (15 - 2 * p) : 99;   // B's phase switch (1..15)

    auto KT = [&](int t) { return role ? (t < tts ? 17 + t : t - tts) : t; };

    int qw0 = hi * 128 + wv * 32;        // wave's first q row (phase 0)
    int qme = qw0 + l31;

    uint koff[4], voff[4];
#pragma unroll
    for (int i = 0; i < 4; ++i) {
        int r  = (wv * 4 + i) * 4 + (lane >> 4);   // LDS row 0..63
        int c  = lane & 15;                        // physical 16B chunk
        int cs = c ^ (r & 15);                     // logical chunk at source
        koff[i] = (uint)(r * (QKVLD * 2) + cs * 16);           // K[key=r][d=cs*8]
        int d   = r + ((cs >> 3) << 6);                        // V^T row packing
        voff[i] = (uint)(d * (T_ * 2) + (cs & 7) * 16);        // V^T[d][t=(cs&7)*8]
    }
    const char* kg = (const char*)(qkv + (size_t)b * T_ * QKVLD + KOFF + kv * HD_);
    const char* vg = (const char*)(vbT + ((size_t)(b * NKV_ + kv) * HD_) * T_);

    uint off8[8];
#pragma unroll
    for (int s = 0; s < 8; ++s)
        off8[s] = (uint)(l31 * 256 + ((((s << 1) + h32) ^ (l31 & 15)) << 4));

#define STAGE(BUF, KN)                                                        \
    {                                                                         \
        const char* kp = kg + (size_t)(KN) * (64 * QKVLD * 2);                \
        const char* vp = vg + (size_t)(KN) * (64 * 2);                        \
        __bf16* kl = &Ks[BUF][(wv * 4) * 512];                                \
        __bf16* vl = &Vs[BUF][(wv * 4) * 512];                                \
        _Pragma("unroll")                                                     \
        for (int i = 0; i < 4; ++i) gload_lds16(kp + koff[i], kl + i * 512);  \
        _Pragma("unroll")                                                     \
        for (int i = 0; i < 4; ++i) gload_lds16(vp + voff[i], vl + i * 512);  \
    }

    bf16x8 qf[8], qf2[8];
    {
        const __bf16* qp = qkv + (size_t)(b * T_ + hi * 128 + wv * 32 + l31) * QKVLD + h * HD_ + h32 * 8;
#pragma unroll
        for (int s = 0; s < 8; ++s) qf[s] = *(const bf16x8*)(qp + s * 16);
        const __bf16* qp2 = qkv + (size_t)(b * T_ + lo * 128 + wv * 32 + l31) * QKVLD + h * HD_ + h32 * 8;
#pragma unroll
        for (int s = 0; s < 8; ++s) qf2[s] = *(const bf16x8*)(qp2 + s * 16);
    }

    f32x16 o[4];
#pragma unroll
    for (int dt = 0; dt < 4; ++dt)
#pragma unroll
        for (int r = 0; r < 16; ++r) o[dt][r] = 0.f;
    float l_p = 0.f;

#define STORE_PARTIAL(PO, PL)                                                   \
    {                                                                           \
        float lsum = l_p + __shfl_xor(l_p, 32, 64);                             \
        int qloc = wv * 32 + l31;                                               \
        float* po = (PO) + ((size_t)slot * 128 + qloc) * 128;                   \
        _Pragma("unroll")                                                       \
        for (int dt = 0; dt < 4; ++dt)                                          \
            _Pragma("unroll")                                                   \
            for (int g = 0; g < 4; ++g) {                                       \
                float4 f = {o[dt][4 * g + 0], o[dt][4 * g + 1],                 \
                            o[dt][4 * g + 2], o[dt][4 * g + 3]};                \
                *(float4*)&po[dt * 32 + 8 * g + 4 * h32] = f;                   \
            }                                                                   \
        if (h32 == 0) (PL)[slot * 128 + qloc] = lsum;                           \
    }

#define TILE_BODY(TT, BUFC)                                                     \
    {                                                                           \
        const int tt_ = (TT);                                                   \
        asm volatile("s_waitcnt vmcnt(0)" ::: "memory");                        \
        __syncthreads();                                                        \
        if (tt_ + 1 < 17) { int kn_ = KT(tt_ + 1); STAGE(1 - (BUFC), kn_); }    \
        if (role && tt_ == tts) {                                               \
            STORE_PARTIAL(pOB, pLB);                                            \
            _Pragma("unroll")                                                   \
            for (int dt = 0; dt < 4; ++dt)                                      \
                _Pragma("unroll")                                               \
                for (int r = 0; r < 16; ++r) o[dt][r] = 0.f;                    \
            l_p = 0.f;                                                          \
            _Pragma("unroll")                                                   \
            for (int s = 0; s < 8; ++s) qf[s] = qf2[s];                         \
            qw0 = lo * 128 + wv * 32;                                           \
            qme = qw0 + l31;                                                    \
        }                                                                       \
        const int s0 = KT(tt_) << 6;                                            \
        if (s0 <= qw0 + 31) {                                                   \
            const char* Kb = (const char*)&Ks[BUFC][0];                         \
            const char* Vb = (const char*)&Vs[BUFC][0];                         \
            f32x16 S0, S1;                                                      \
            _Pragma("unroll")                                                   \
            for (int r = 0; r < 16; ++r) { S0[r] = 0.f; S1[r] = 0.f; }          \
            __builtin_amdgcn_s_setprio(1);                                      \
            _Pragma("unroll")                                                   \
            for (int s = 0; s < 8; ++s) {                                       \
                bf16x8 kf0 = *(const bf16x8*)(Kb + off8[s]);                    \
                bf16x8 kf1 = *(const bf16x8*)(Kb + off8[s] + 8192);             \
                S0 = __builtin_amdgcn_mfma_f32_32x32x16_bf16(kf0, qf[s], S0, 0, 0, 0); \
                S1 = __builtin_amdgcn_mfma_f32_32x32x16_bf16(kf1, qf[s], S1, 0, 0, 0); \
            }                                                                   \
            __builtin_amdgcn_s_setprio(0);                                      \
            const bool domask = (s0 + 63 > qw0);                                \
            uint w[16];                                                         \
            _Pragma("unroll")                                                   \
            for (int i = 0; i < 8; ++i) {                                       \
                const int r0 = 2 * i;                                           \
                float e0 = EXP2F(S0[r0]);                                       \
                float e1 = EXP2F(S0[r0 + 1]);                                   \
                if (domask) {                                                   \
                    int k0 = s0 + (r0 & 3) + 8 * (r0 >> 2) + 4 * h32;           \
                    if (k0     > qme) e0 = 0.f;                                 \
                    if (k0 + 1 > qme) e1 = 0.f;                                 \
                }                                                               \
                l_p += e0 + e1;                                                 \
                union { __bf16 h2[2]; uint u; } pk;                             \
                pk.h2[0] = (__bf16)e0; pk.h2[1] = (__bf16)e1;                   \
                w[i] = pk.u;                                                    \
            }                                                                   \
            _Pragma("unroll")                                                   \
            for (int i = 0; i < 8; ++i) {                                       \
                const int r0 = 2 * i;                                           \
                float e0 = EXP2F(S1[r0]);                                       \
                float e1 = EXP2F(S1[r0 + 1]);                                   \
                if (domask) {                                                   \
                    int k0 = s0 + 32 + (r0 & 3) + 8 * (r0 >> 2) + 4 * h32;      \
                    if (k0     > qme) e0 = 0.f;                                 \
                    if (k0 + 1 > qme) e1 = 0.f;                                 \
                }                                                               \
                l_p += e0 + e1;                                                 \
                union { __bf16 h2[2]; uint u; } pk;                             \
                pk.h2[0] = (__bf16)e0; pk.h2[1] = (__bf16)e1;                   \
                w[8 + i] = pk.u;                                                \
            }                                                                   \
            union U8 { uint u[4]; bf16x8 v; };                                  \
            bf16x8 pf[4];                                                       \
            _Pragma("unroll")                                                   \
            for (int ks = 0; ks < 4; ++ks) {                                    \
                const int bsel = ((ks >> 1) << 3) + ((ks & 1) << 2);            \
                uint a0 = w[bsel],     b0 = w[bsel + 2];                        \
                uint a1 = w[bsel + 1], b1 = w[bsel + 3];                        \
                asm("v_permlane32_swap_b32 %0, %1" : "+v"(a0), "+v"(b0));       \
                asm("v_permlane32_swap_b32 %0, %1" : "+v"(a1), "+v"(b1));       \
                U8 t;                                                           \
                t.u[0] = a0; t.u[1] = a1; t.u[2] = b0; t.u[3] = b1;             \
                pf[ks] = t.v;                                                   \
            }                                                                   \
            __builtin_amdgcn_s_setprio(1);                                      \
            _Pragma("unroll")                                                   \
            for (int dt = 0; dt < 4; ++dt) {                                    \
                const int ab = (dt >> 1) << 2;                                  \
                const int hf = (dt & 1) * 8192;                                 \
                _Pragma("unroll")                                               \
                for (int ks = 0; ks < 4; ++ks) {                                \
                    bf16x8 vf = *(const bf16x8*)(Vb + off8[ab + ks] + hf);      \
                    o[dt] = __builtin_amdgcn_mfma_f32_32x32x16_bf16(vf, pf[ks], o[dt], 0, 0, 0); \
                }                                                               \
            }                                                                   \
            __builtin_amdgcn_s_setprio(0);                                      \
        }                                                                       \
    }

    STAGE(0, KT(0));

    for (int tt = 0; tt < 16; tt += 2) {
        TILE_BODY(tt, 0);
        TILE_BODY(tt + 1, 1);
    }
    TILE_BODY(16, 0);

    if (role == 0) {
        STORE_PARTIAL(pOA, pLA);
    } else {
        float l  = l_p + __shfl_xor(l_p, 32, 64);
        float inv = 1.f / l;
        __bf16* yp = y + (size_t)(b * T_ + qw0 + l31) * C_ + h * HD_;
#pragma unroll
        for (int dt = 0; dt < 4; ++dt)
#pragma unroll
            for (int g = 0; g < 4; ++g) {
                union { __bf16 h4[4]; uint2 u; } pk;
#pragma unroll
                for (int e = 0; e < 4; ++e) pk.h4[e] = (__bf16)(o[dt][4 * g + e] * inv);
                *(uint2*)&yp[dt * 32 + 8 * g + 4 * h32] = pk.u;
            }
    }
#undef TILE_BODY
#undef STORE_PARTIAL
#undef STAGE
}

// ---------------------------------------------------------------------------
// Combine hi-tile partials: y = (oA + oB) / (lA + lB).  256 blocks x 256 thr.
// ---------------------------------------------------------------------------
__global__ __launch_bounds__(256) void attn_combine(const float* __restrict__ pOA,
                                                    const float* __restrict__ pOB,
                                                    const float* __restrict__ pLA,
                                                    const float* __restrict__ pLB,
                                                    __bf16* __restrict__ y)
{
    int slot = blockIdx.x;               // p*32 + bh
    int p  = slot >> 5, bh = slot & 31;
    int b  = bh >> 4,   h  = bh & 15;
    int hi = 15 - p;
    int t  = threadIdx.x;
    int q  = t >> 1;                     // 0..127
    int dh = (t & 1) << 6;               // 0 or 64

    float inv = 1.f / (pLA[slot * 128 + q] + pLB[slot * 128 + q]);
    size_t base = ((size_t)slot * 128 + q) * 128 + dh;
    __bf16* yp = y + (size_t)(b * T_ + hi * 128 + q) * C_ + h * HD_ + dh;
#pragma unroll
    for (int d0 = 0; d0 < 64; d0 += 8) {
        float4 a0 = *(const float4*)&pOA[base + d0];
        float4 a1 = *(const float4*)&pOA[base + d0 + 4];
        float4 b0 = *(const float4*)&pOB[base + d0];
        float4 b1 = *(const float4*)&pOB[base + d0 + 4];
        union { __bf16 h8[8]; uint4 u; } pk;
        pk.h8[0] = (__bf16)((a0.x + b0.x) * inv);
        pk.h8[1] = (__bf16)((a0.y + b0.y) * inv);
        pk.h8[2] = (__bf16)((a0.z + b0.z) * inv);
        pk.h8[3] = (__bf16)((a0.w + b0.w) * inv);
        pk.h8[4] = (__bf16)((a1.x + b1.x) * inv);
        pk.h8[5] = (__bf16)((a1.y + b1.y) * inv);
        pk.h8[6] = (__bf16)((a1.z + b1.z) * inv);
        pk.h8[7] = (__bf16)((a1.w + b1.w) * inv);
        *(uint4*)&yp[d0] = pk.u;
    }
}

// ---------------------------------------------------------------------------
extern "C" void kernel_launch(void* const* d_in, const int* in_sizes, int n_in,
                              void* d_out, int out_size, void* d_ws, size_t ws_size,
                              hipStream_t stream)
{
    const float* x    = (const float*)d_in[0];
    const float* cosb = (const float*)d_in[1];
    const float* sinb = (const float*)d_in[2];
    const float* Wq   = (const float*)d_in[3];
    const float* Wk   = (const float*)d_in[4];
    const float* Wv   = (const float*)d_in[5];
    const float* Wp   = (const float*)d_in[6];
    float* out = (float*)d_out;

    const int M = B_ * T_;   // 4096

    // workspace: xb | qkv | wqkvT | wpT | vt | y | pOB   (~101 MB)
    // pOA aliases xb (dead after gemm1); pL* alias wqkvT.
    char* w = (char*)d_ws;
    __bf16* xb    = (__bf16*)w;  w += (size_t)M * C_ * 2;
    __bf16* qkv   = (__bf16*)w;  w += (size_t)M * QKVLD * 2;
    __bf16* wqkvT = (__bf16*)w;  w += (size_t)QKVLD * C_ * 2;
    __bf16* wpT   = (__bf16*)w;  w += (size_t)C_ * C_ * 2;
    __bf16* vt    = (__bf16*)w;  w += (size_t)M * NKV_ * HD_ * 2;
    __bf16* y     = (__bf16*)w;  w += (size_t)M * C_ * 2;
    float*  pOB   = (float*)w;
    float*  pOA   = (float*)xb;
    float*  pLA   = (float*)wqkvT;
    float*  pLB   = pLA + 8 * 32 * 128;

    // fused preprocessing (cast + both weight transposes): 1 launch
    prep<<<14336, 256, 0, stream>>>(x, Wq, Wk, Wv, Wp, xb, wqkvT, wpT);

    // fused QKV projection (bf16 MFMA, dbuf, XCD-chunked; grid 768 % 8 == 0)
    gemm_bt<__bf16><<<dim3(QKVLD / 128, M / 128), 256, 0, stream>>>(xb, wqkvT, qkv, M, QKVLD, C_, QKVLD);

    // RoPE+RMSNorm (q+k) + V transpose: 1 launch
    rope_vt<<<20992, 256, 0, stream>>>(qkv, cosb, sinb, vt);

    // flash attention v10 + separate combine
    attn32<<<512, 256, 0, stream>>>(qkv, vt, y, pOA, pOB, pLA, pLB);
    attn_combine<<<256, 256, 0, stream>>>(pOA, pOB, pLA, pLB, y);

    // output projection (bf16 MFMA, fp32 out, dbuf, XCD-chunked; grid 512 % 8 == 0)
    gemm_bt<float><<<dim3(C_ / 128, M / 128), 256, 0, stream>>>(y, wpT, out, M, C_, C_, C_);
}

// Round 14
// 301.294 us; speedup vs baseline: 1.0379x; 1.0166x over previous
//
#include <hip/hip_runtime.h>
#include <hip/hip_bf16.h>
#include <math.h>

// Problem constants (CausalSelfAttention_84928683311105)
#define B_  2
#define T_  2048
#define C_  2048
#define NH_ 16
#define NKV_ 4
#define HD_ 128
#define NREP_ (NH_/NKV_)     // 4

// fused QKV output layout: [B*T, 3072] ; q @ 0, k @ 2048, v @ 2560
#define QKVLD 3072
#define KOFF  2048
#define VOFF  2560

// q scale: (1/sqrt(d))^2 folded = 1/128, times log2(e) so scores are in
// log2 units and softmax exp is a single native v_exp_f32.
#define QSCALE 0.01127105500694502f

// fast exp2: bare v_exp_f32 when the builtin exists (libm exp2f adds guards)
#if defined(__has_builtin)
# if __has_builtin(__builtin_amdgcn_exp2f)
#  define EXP2F(x) __builtin_amdgcn_exp2f(x)
# else
#  define EXP2F(x) exp2f(x)
# endif
#else
# define EXP2F(x) exp2f(x)
#endif

typedef __bf16 bf16x8 __attribute__((ext_vector_type(8)));
typedef float  f32x4  __attribute__((ext_vector_type(4)));
typedef float  f32x16 __attribute__((ext_vector_type(16)));

__device__ inline void gload_lds16(const void* g, void* l) {
    __builtin_amdgcn_global_load_lds((const __attribute__((address_space(1))) void*)g,
                                     (__attribute__((address_space(3))) void*)l, 16, 0, 0);
}

// ---------------------------------------------------------------------------
// prep: cast_bf16 + wtrans_qkv + wtrans(Wp) fused into one launch.
// ---------------------------------------------------------------------------
__global__ __launch_bounds__(256) void prep(const float* __restrict__ x,
                                            const float* __restrict__ Wq,
                                            const float* __restrict__ Wk,
                                            const float* __restrict__ Wv,
                                            const float* __restrict__ Wp,
                                            __bf16* __restrict__ xb,
                                            __bf16* __restrict__ wqkvT,
                                            __bf16* __restrict__ wpT)
{
    __shared__ float tl[32][33];
    const int bx  = blockIdx.x;
    const int tid = threadIdx.x;

    if (bx < 4096) {
        size_t i = ((size_t)bx * 256 + tid) * 8;
        float4 a = *(const float4*)&x[i];
        float4 b = *(const float4*)&x[i + 4];
        union { __bf16 h[8]; uint4 u; } pk;
        pk.h[0] = (__bf16)a.x; pk.h[1] = (__bf16)a.y; pk.h[2] = (__bf16)a.z; pk.h[3] = (__bf16)a.w;
        pk.h[4] = (__bf16)b.x; pk.h[5] = (__bf16)b.y; pk.h[6] = (__bf16)b.z; pk.h[7] = (__bf16)b.w;
        *(uint4*)&xb[i] = pk.u;
        return;
    }

    const float* src;
    int ncols, c0, dr0, k0;
    if (bx < 10240) {
        int r  = bx - 4096;
        int ct = r % 96;
        k0 = (r / 96) * 32;
        if (ct < 64)      { src = Wq; ncols = 2048; c0 = ct * 32;        dr0 = ct * 32; }
        else if (ct < 80) { src = Wk; ncols = 512;  c0 = (ct - 64) * 32; dr0 = KOFF + (ct - 64) * 32; }
        else              { src = Wv; ncols = 512;  c0 = (ct - 80) * 32; dr0 = VOFF + (ct - 80) * 32; }
    } else {
        int r  = bx - 10240;
        src = Wp; ncols = 2048;
        c0  = (r & 63) * 32; dr0 = c0;
        k0  = (r >> 6) * 32;
    }
    __bf16* dst = (bx < 10240) ? wqkvT : wpT;

    int rr = tid >> 3;
    int c4 = (tid & 7) * 4;
    float4 v = *(const float4*)&src[(size_t)(k0 + rr) * ncols + c0 + c4];
    tl[rr][c4] = v.x; tl[rr][c4 + 1] = v.y; tl[rr][c4 + 2] = v.z; tl[rr][c4 + 3] = v.w;
    __syncthreads();
    union { __bf16 h[4]; uint2 u; } pk;
#pragma unroll
    for (int j = 0; j < 4; ++j) pk.h[j] = (__bf16)tl[c4 + j][rr];
    *(uint2*)&dst[(size_t)(dr0 + rr) * 2048 + k0 + c4] = pk.u;
}

// ---------------------------------------------------------------------------
// bf16 MFMA GEMM, single-barrier double-buffered: C = A(MxK) @ Bt^T, Bt [N,K].
// 128x128 tile, BK=32, 4 waves, global_load_lds(16B) prefetch into alt buffer.
// XCD-chunked block swizzle (T1); grid must satisfy (gx*gy) % 8 == 0.
//
// v15: QKV template mode fuses RoPE+RMSNorm into the epilogue. Col-tiles are
// head-aligned (128 wide), so each q/k block's C tile holds COMPLETE head
// vectors for 128 tokens. The K-loop's staging LDS (As|Bs = 32KB) is dead at
// epilogue time and is exactly a [128][128] bf16 buffer: park the tile there,
// then wave-per-row: lane=d loads the (d, d+64) RoPE pair, rotates, 6-step
// shfl_xor butterfly for the RMS sum, scales (QSCALE for q / 1.0 for k),
// stores. Numerically identical to the old separate rope pass (it also read
// bf16-rounded GEMM output). V blocks (col0 >= VOFF) keep the plain store.
// Deletes ~42MB of HBM roundtrip + most of the rope_vt kernel.
// ---------------------------------------------------------------------------
template<typename TOUT, bool QKV>
__global__ __launch_bounds__(256) void gemm_bt(const __bf16* __restrict__ A,
                                               const __bf16* __restrict__ Bt,
                                               TOUT* __restrict__ C,
                                               int M, int N, int K, int ldc,
                                               const float* __restrict__ cosb,
                                               const float* __restrict__ sinb)
{
    __shared__ __bf16 smem[16384];       // As[2][4096] | Bs[2][4096]; epi: [128][128]
#define ASP(b) (smem + (b) * 4096)
#define BSP(b) (smem + 8192 + (b) * 4096)

    const int tid  = threadIdx.x;
    const int wv   = tid >> 6;
    const int lane = tid & 63;
    const int grp  = lane >> 4;
    const int id16 = lane & 15;
    const int wr   = wv >> 1;
    const int wc   = wv & 1;

    // XCD-chunked bijective swizzle of the flattened block id
    const int gx  = gridDim.x;
    const int nwg = gx * gridDim.y;
    const int q8  = nwg >> 3;
    const int lid = blockIdx.x + gx * blockIdx.y;
    const int swz = (lid & 7) * q8 + (lid >> 3);
    const int row0 = (swz / gx) * 128;
    const int col0 = (swz % gx) * 128;

    const int sm = tid >> 2;
    const int sk = (tid & 3) << 3;

    const __bf16* ga0 = A  + (size_t)(row0 + sm) * K + sk;
    const __bf16* ga1 = A  + (size_t)(row0 + 64 + sm) * K + sk;
    const __bf16* gb0 = Bt + (size_t)(col0 + sm) * K + sk;
    const __bf16* gb1 = Bt + (size_t)(col0 + 64 + sm) * K + sk;

    f32x4 acc[4][4];
    const f32x4 fz = {0.f, 0.f, 0.f, 0.f};
#pragma unroll
    for (int i = 0; i < 4; ++i)
#pragma unroll
        for (int j = 0; j < 4; ++j) acc[i][j] = fz;

    const int nk = K >> 5;

    // prologue: stage tile 0 into buf 0
    {
        __bf16* a0 = ASP(0) + (wv << 9);
        __bf16* b0 = BSP(0) + (wv << 9);
        gload_lds16(ga0, a0);
        gload_lds16(ga1, a0 + 2048);
        gload_lds16(gb0, b0);
        gload_lds16(gb1, b0 + 2048);
    }

    for (int kt = 0; kt < nk; ++kt) {
        const int bufc = kt & 1;
        asm volatile("s_waitcnt vmcnt(0)" ::: "memory");
        __syncthreads();

        if (kt + 1 < nk) {
            const int kb = (kt + 1) << 5;
            __bf16* a0 = ASP(1 - bufc) + (wv << 9);
            __bf16* b0 = BSP(1 - bufc) + (wv << 9);
            gload_lds16(ga0 + kb, a0);
            gload_lds16(ga1 + kb, a0 + 2048);
            gload_lds16(gb0 + kb, b0);
            gload_lds16(gb1 + kb, b0 + 2048);
        }

        bf16x8 af[4], bfr[4];
#pragma unroll
        for (int i = 0; i < 4; ++i)
            af[i] = *(const bf16x8*)(ASP(bufc) + ((wr << 6) + (i << 4) + id16) * 32 + (grp << 3));
#pragma unroll
        for (int j = 0; j < 4; ++j)
            bfr[j] = *(const bf16x8*)(BSP(bufc) + ((wc << 6) + (j << 4) + id16) * 32 + (grp << 3));
#pragma unroll
        for (int i = 0; i < 4; ++i)
#pragma unroll
            for (int j = 0; j < 4; ++j)
                acc[i][j] = __builtin_amdgcn_mfma_f32_16x16x32_bf16(af[i], bfr[j], acc[i][j], 0, 0, 0);
    }

    if constexpr (QKV) {
        if (col0 < VOFF) {
            // ---- fused RoPE + RMSNorm epilogue (q/k blocks) ----
            __syncthreads();                       // staging LDS now dead
            __bf16 (*EB)[128] = (__bf16(*)[128])smem;
#pragma unroll
            for (int i = 0; i < 4; ++i)
#pragma unroll
                for (int j = 0; j < 4; ++j)
#pragma unroll
                    for (int r = 0; r < 4; ++r)
                        EB[(wr << 6) + (i << 4) + (grp << 2) + r][(wc << 6) + (j << 4) + id16] =
                            (__bf16)acc[i][j][r];
            __syncthreads();

            const float scale = (col0 < KOFF) ? QSCALE : 1.0f;
            for (int ri = 0; ri < 32; ++ri) {
                const int lrow = (wv << 5) + ri;
                const int grow = row0 + lrow;
                const int t = grow & (T_ - 1);
                float c = cosb[t * 64 + lane];
                float s = sinb[t * 64 + lane];
                float x1 = (float)EB[lrow][lane];
                float x2 = (float)EB[lrow][lane + 64];
                float r1 = x1 * c - x2 * s;
                float r2 = x1 * s + x2 * c;
                float ss = r1 * r1 + r2 * r2;
#pragma unroll
                for (int off = 32; off; off >>= 1) ss += __shfl_xor(ss, off, 64);
                float inv = rsqrtf(ss * (1.f / 128.f) + 1e-6f) * scale;
                TOUT* qp = C + (size_t)grow * ldc + col0;
                qp[lane]      = (TOUT)(r1 * inv);
                qp[lane + 64] = (TOUT)(r2 * inv);
            }
            return;
        }
    }

    // ---- plain epilogue (V blocks and out-projection) ----
#pragma unroll
    for (int i = 0; i < 4; ++i) {
        int gr = row0 + (wr << 6) + (i << 4) + (grp << 2);
#pragma unroll
        for (int j = 0; j < 4; ++j) {
            int gc = col0 + (wc << 6) + (j << 4) + id16;
#pragma unroll
            for (int r = 0; r < 4; ++r) {
                if constexpr (sizeof(TOUT) == 4)
                    C[(size_t)(gr + r) * ldc + gc] = acc[i][j][r];
                else
                    C[(size_t)(gr + r) * ldc + gc] = (TOUT)acc[i][j][r];
            }
        }
    }
#undef ASP
#undef BSP
}

// ---------------------------------------------------------------------------
// vtrans: V out of qkv -> vt [B,NKV,128,T] bf16.  512 blocks.
// ---------------------------------------------------------------------------
__global__ __launch_bounds__(256) void vtrans(const __bf16* __restrict__ qkv,
                                              __bf16* __restrict__ vt)
{
    __shared__ __bf16 tl[32][HD_ + 8];
    const int bx  = blockIdx.x;
    const int tid = threadIdx.x;
    int st  = bx & 63;
    int bkv = bx >> 6;
    int b = bkv >> 2, kv = bkv & 3;
    int s0 = st << 5;
    {
        int s = tid >> 3;
        int d = (tid & 7) << 4;
        const __bf16* src = qkv + (size_t)(b * T_ + s0 + s) * QKVLD + VOFF + kv * HD_ + d;
        *(bf16x8*)&tl[s][d]     = *(const bf16x8*)src;
        *(bf16x8*)&tl[s][d + 8] = *(const bf16x8*)(src + 8);
    }
    __syncthreads();
    {
        int d  = tid >> 1;
        int sh = (tid & 1) << 4;
        __bf16 tmp[16];
#pragma unroll
        for (int j = 0; j < 16; ++j) tmp[j] = tl[sh + j][d];
        __bf16* dst = vt + ((size_t)(b * NKV_ + kv) * HD_ + d) * T_ + s0 + sh;
        *(bf16x8*)dst       = *(bf16x8*)&tmp[0];
        *(bf16x8*)(dst + 8) = *(bf16x8*)&tmp[8];
    }
}

// ---------------------------------------------------------------------------
// Flash attention v10 (unchanged from R8 best): uniform 17-tile A/B blocks,
// KVBLK=64, 32x32 MFMA, in-register softmax, permlane32_swap half-exchange,
// fast exp2, hoisted LDS offsets, XCD clustering, separate combine kernel.
// ---------------------------------------------------------------------------
__global__ __launch_bounds__(256, 2) void attn32(const __bf16* __restrict__ qkv,
                                                 const __bf16* __restrict__ vbT,
                                                 __bf16* __restrict__ y,
                                                 float* __restrict__ pOA,
                                                 float* __restrict__ pOB,
                                                 float* __restrict__ pLA,
                                                 float* __restrict__ pLB)
{
    __shared__ __bf16 Ks[2][64 * 128];   // [key][d] , chunk16 ^ (row&15)
    __shared__ __bf16 Vs[2][64 * 128];   // row r: d=r keys0..63 | d=r+64 keys0..63

    const int tid  = threadIdx.x;
    const int wv   = tid >> 6;
    const int lane = tid & 63;
    const int l31  = lane & 31;
    const int h32  = lane >> 5;

    // XCD-clustered decode: cluster (b,kv) = bx&7; member = bx>>3.
    const int bx   = blockIdx.x;         // 512
    const int b    = (bx >> 2) & 1;
    const int kv   = bx & 3;
    const int m    = bx >> 3;            // 0..63
    const int hh   = m & 3;
    const int role = (m >> 2) & 1;       // 0 = A (hi prefix), 1 = B (hi rest + lo)
    const int p    = m >> 3;             // 0..7
    const int h    = kv * 4 + hh;
    const int bh   = b * 16 + h;
    const int slot = p * 32 + bh;

    const int hi  = 15 - p;              // 8..15
    const int lo  = p;                   // 0..7
    const int tts = role ? (15 - 2 * p) : 99;   // B's phase switch (1..15)

    auto KT = [&](int t) { return role ? (t < tts ? 17 + t : t - tts) : t; };

    int qw0 = hi * 128 + wv * 32;        // wave's first q row (phase 0)
    int qme = qw0 + l31;

    uint koff[4], voff[4];
#pragma unroll
    for (int i = 0; i < 4; ++i) {
        int r  = (wv * 4 + i) * 4 + (lane >> 4);   // LDS row 0..63
        int c  = lane & 15;                        // physical 16B chunk
        int cs = c ^ (r & 15);                     // logical chunk at source
        koff[i] = (uint)(r * (QKVLD * 2) + cs * 16);           // K[key=r][d=cs*8]
        int d   = r + ((cs >> 3) << 6);                        // V^T row packing
        voff[i] = (uint)(d * (T_ * 2) + (cs & 7) * 16);        // V^T[d][t=(cs&7)*8]
    }
    const char* kg = (const char*)(qkv + (size_t)b * T_ * QKVLD + KOFF + kv * HD_);
    const char* vg = (const char*)(vbT + ((size_t)(b * NKV_ + kv) * HD_) * T_);

    uint off8[8];
#pragma unroll
    for (int s = 0; s < 8; ++s)
        off8[s] = (uint)(l31 * 256 + ((((s << 1) + h32) ^ (l31 & 15)) << 4));

#define STAGE(BUF, KN)                                                        \
    {                                                                         \
        const char* kp = kg + (size_t)(KN) * (64 * QKVLD * 2);                \
        const char* vp = vg + (size_t)(KN) * (64 * 2);                        \
        __bf16* kl = &Ks[BUF][(wv * 4) * 512];                                \
        __bf16* vl = &Vs[BUF][(wv * 4) * 512];                                \
        _Pragma("unroll")                                                     \
        for (int i = 0; i < 4; ++i) gload_lds16(kp + koff[i], kl + i * 512);  \
        _Pragma("unroll")                                                     \
        for (int i = 0; i < 4; ++i) gload_lds16(vp + voff[i], vl + i * 512);  \
    }

    bf16x8 qf[8], qf2[8];
    {
        const __bf16* qp = qkv + (size_t)(b * T_ + hi * 128 + wv * 32 + l31) * QKVLD + h * HD_ + h32 * 8;
#pragma unroll
        for (int s = 0; s < 8; ++s) qf[s] = *(const bf16x8*)(qp + s * 16);
        const __bf16* qp2 = qkv + (size_t)(b * T_ + lo * 128 + wv * 32 + l31) * QKVLD + h * HD_ + h32 * 8;
#pragma unroll
        for (int s = 0; s < 8; ++s) qf2[s] = *(const bf16x8*)(qp2 + s * 16);
    }

    f32x16 o[4];
#pragma unroll
    for (int dt = 0; dt < 4; ++dt)
#pragma unroll
        for (int r = 0; r < 16; ++r) o[dt][r] = 0.f;
    float l_p = 0.f;

#define STORE_PARTIAL(PO, PL)                                                   \
    {                                                                           \
        float lsum = l_p + __shfl_xor(l_p, 32, 64);                             \
        int qloc = wv * 32 + l31;                                               \
        float* po = (PO) + ((size_t)slot * 128 + qloc) * 128;                   \
        _Pragma("unroll")                                                       \
        for (int dt = 0; dt < 4; ++dt)                                          \
            _Pragma("unroll")                                                   \
            for (int g = 0; g < 4; ++g) {                                       \
                float4 f = {o[dt][4 * g + 0], o[dt][4 * g + 1],                 \
                            o[dt][4 * g + 2], o[dt][4 * g + 3]};                \
                *(float4*)&po[dt * 32 + 8 * g + 4 * h32] = f;                   \
            }                                                                   \
        if (h32 == 0) (PL)[slot * 128 + qloc] = lsum;                           \
    }

#define TILE_BODY(TT, BUFC)                                                     \
    {                                                                           \
        const int tt_ = (TT);                                                   \
        asm volatile("s_waitcnt vmcnt(0)" ::: "memory");                        \
        __syncthreads();                                                        \
        if (tt_ + 1 < 17) { int kn_ = KT(tt_ + 1); STAGE(1 - (BUFC), kn_); }    \
        if (role && tt_ == tts) {                                               \
            STORE_PARTIAL(pOB, pLB);                                            \
            _Pragma("unroll")                                                   \
            for (int dt = 0; dt < 4; ++dt)                                      \
                _Pragma("unroll")                                               \
                for (int r = 0; r < 16; ++r) o[dt][r] = 0.f;                    \
            l_p = 0.f;                                                          \
            _Pragma("unroll")                                                   \
            for (int s = 0; s < 8; ++s) qf[s] = qf2[s];                         \
            qw0 = lo * 128 + wv * 32;                                           \
            qme = qw0 + l31;                                                    \
        }                                                                       \
        const int s0 = KT(tt_) << 6;                                            \
        if (s0 <= qw0 + 31) {                                                   \
            const char* Kb = (const char*)&Ks[BUFC][0];                         \
            const char* Vb = (const char*)&Vs[BUFC][0];                         \
            f32x16 S0, S1;                                                      \
            _Pragma("unroll")                                                   \
            for (int r = 0; r < 16; ++r) { S0[r] = 0.f; S1[r] = 0.f; }          \
            __builtin_amdgcn_s_setprio(1);                                      \
            _Pragma("unroll")                                                   \
            for (int s = 0; s < 8; ++s) {                                       \
                bf16x8 kf0 = *(const bf16x8*)(Kb + off8[s]);                    \
                bf16x8 kf1 = *(const bf16x8*)(Kb + off8[s] + 8192);             \
                S0 = __builtin_amdgcn_mfma_f32_32x32x16_bf16(kf0, qf[s], S0, 0, 0, 0); \
                S1 = __builtin_amdgcn_mfma_f32_32x32x16_bf16(kf1, qf[s], S1, 0, 0, 0); \
            }                                                                   \
            __builtin_amdgcn_s_setprio(0);                                      \
            const bool domask = (s0 + 63 > qw0);                                \
            uint w[16];                                                         \
            _Pragma("unroll")                                                   \
            for (int i = 0; i < 8; ++i) {                                       \
                const int r0 = 2 * i;                                           \
                float e0 = EXP2F(S0[r0]);                                       \
                float e1 = EXP2F(S0[r0 + 1]);                                   \
                if (domask) {                                                   \
                    int k0 = s0 + (r0 & 3) + 8 * (r0 >> 2) + 4 * h32;           \
                    if (k0     > qme) e0 = 0.f;                                 \
                    if (k0 + 1 > qme) e1 = 0.f;                                 \
                }                                                               \
                l_p += e0 + e1;                                                 \
                union { __bf16 h2[2]; uint u; } pk;                             \
                pk.h2[0] = (__bf16)e0; pk.h2[1] = (__bf16)e1;                   \
                w[i] = pk.u;                                                    \
            }                                                                   \
            _Pragma("unroll")                                                   \
            for (int i = 0; i < 8; ++i) {                                       \
                const int r0 = 2 * i;                                           \
                float e0 = EXP2F(S1[r0]);                                       \
                float e1 = EXP2F(S1[r0 + 1]);                                   \
                if (domask) {                                                   \
                    int k0 = s0 + 32 + (r0 & 3) + 8 * (r0 >> 2) + 4 * h32;      \
                    if (k0     > qme) e0 = 0.f;                                 \
                    if (k0 + 1 > qme) e1 = 0.f;                                 \
                }                                                               \
                l_p += e0 + e1;                                                 \
                union { __bf16 h2[2]; uint u; } pk;                             \
                pk.h2[0] = (__bf16)e0; pk.h2[1] = (__bf16)e1;                   \
                w[8 + i] = pk.u;                                                \
            }                                                                   \
            union U8 { uint u[4]; bf16x8 v; };                                  \
            bf16x8 pf[4];                                                       \
            _Pragma("unroll")                                                   \
            for (int ks = 0; ks < 4; ++ks) {                                    \
                const int bsel = ((ks >> 1) << 3) + ((ks & 1) << 2);            \
                uint a0 = w[bsel],     b0 = w[bsel + 2];                        \
                uint a1 = w[bsel + 1], b1 = w[bsel + 3];                        \
                asm("v_permlane32_swap_b32 %0, %1" : "+v"(a0), "+v"(b0));       \
                asm("v_permlane32_swap_b32 %0, %1" : "+v"(a1), "+v"(b1));       \
                U8 t;                                                           \
                t.u[0] = a0; t.u[1] = a1; t.u[2] = b0; t.u[3] = b1;             \
                pf[ks] = t.v;                                                   \
            }                                                                   \
            __builtin_amdgcn_s_setprio(1);                                      \
            _Pragma("unroll")                                                   \
            for (int dt = 0; dt < 4; ++dt) {                                    \
                const int ab = (dt >> 1) << 2;                                  \
                const int hf = (dt & 1) * 8192;                                 \
                _Pragma("unroll")                                               \
                for (int ks = 0; ks < 4; ++ks) {                                \
                    bf16x8 vf = *(const bf16x8*)(Vb + off8[ab + ks] + hf);      \
                    o[dt] = __builtin_amdgcn_mfma_f32_32x32x16_bf16(vf, pf[ks], o[dt], 0, 0, 0); \
                }                                                               \
            }                                                                   \
            __builtin_amdgcn_s_setprio(0);                                      \
        }                                                                       \
    }

    STAGE(0, KT(0));

    for (int tt = 0; tt < 16; tt += 2) {
        TILE_BODY(tt, 0);
        TILE_BODY(tt + 1, 1);
    }
    TILE_BODY(16, 0);

    if (role == 0) {
        STORE_PARTIAL(pOA, pLA);
    } else {
        float l  = l_p + __shfl_xor(l_p, 32, 64);
        float inv = 1.f / l;
        __bf16* yp = y + (size_t)(b * T_ + qw0 + l31) * C_ + h * HD_;
#pragma unroll
        for (int dt = 0; dt < 4; ++dt)
#pragma unroll
            for (int g = 0; g < 4; ++g) {
                union { __bf16 h4[4]; uint2 u; } pk;
#pragma unroll
                for (int e = 0; e < 4; ++e) pk.h4[e] = (__bf16)(o[dt][4 * g + e] * inv);
                *(uint2*)&yp[dt * 32 + 8 * g + 4 * h32] = pk.u;
            }
    }
#undef TILE_BODY
#undef STORE_PARTIAL
#undef STAGE
}

// ---------------------------------------------------------------------------
// Combine hi-tile partials: y = (oA + oB) / (lA + lB).  256 blocks x 256 thr.
// ---------------------------------------------------------------------------
__global__ __launch_bounds__(256) void attn_combine(const float* __restrict__ pOA,
                                                    const float* __restrict__ pOB,
                                                    const float* __restrict__ pLA,
                                                    const float* __restrict__ pLB,
                                                    __bf16* __restrict__ y)
{
    int slot = blockIdx.x;               // p*32 + bh
    int p  = slot >> 5, bh = slot & 31;
    int b  = bh >> 4,   h  = bh & 15;
    int hi = 15 - p;
    int t  = threadIdx.x;
    int q  = t >> 1;                     // 0..127
    int dh = (t & 1) << 6;               // 0 or 64

    float inv = 1.f / (pLA[slot * 128 + q] + pLB[slot * 128 + q]);
    size_t base = ((size_t)slot * 128 + q) * 128 + dh;
    __bf16* yp = y + (size_t)(b * T_ + hi * 128 + q) * C_ + h * HD_ + dh;
#pragma unroll
    for (int d0 = 0; d0 < 64; d0 += 8) {
        float4 a0 = *(const float4*)&pOA[base + d0];
        float4 a1 = *(const float4*)&pOA[base + d0 + 4];
        float4 b0 = *(const float4*)&pOB[base + d0];
        float4 b1 = *(const float4*)&pOB[base + d0 + 4];
        union { __bf16 h8[8]; uint4 u; } pk;
        pk.h8[0] = (__bf16)((a0.x + b0.x) * inv);
        pk.h8[1] = (__bf16)((a0.y + b0.y) * inv);
        pk.h8[2] = (__bf16)((a0.z + b0.z) * inv);
        pk.h8[3] = (__bf16)((a0.w + b0.w) * inv);
        pk.h8[4] = (__bf16)((a1.x + b1.x) * inv);
        pk.h8[5] = (__bf16)((a1.y + b1.y) * inv);
        pk.h8[6] = (__bf16)((a1.z + b1.z) * inv);
        pk.h8[7] = (__bf16)((a1.w + b1.w) * inv);
        *(uint4*)&yp[d0] = pk.u;
    }
}

// ---------------------------------------------------------------------------
extern "C" void kernel_launch(void* const* d_in, const int* in_sizes, int n_in,
                              void* d_out, int out_size, void* d_ws, size_t ws_size,
                              hipStream_t stream)
{
    const float* x    = (const float*)d_in[0];
    const float* cosb = (const float*)d_in[1];
    const float* sinb = (const float*)d_in[2];
    const float* Wq   = (const float*)d_in[3];
    const float* Wk   = (const float*)d_in[4];
    const float* Wv   = (const float*)d_in[5];
    const float* Wp   = (const float*)d_in[6];
    float* out = (float*)d_out;

    const int M = B_ * T_;   // 4096

    // workspace: xb | qkv | wqkvT | wpT | vt | y | pOB   (~101 MB)
    // pOA aliases xb (dead after gemm1); pL* alias wqkvT.
    char* w = (char*)d_ws;
    __bf16* xb    = (__bf16*)w;  w += (size_t)M * C_ * 2;
    __bf16* qkv   = (__bf16*)w;  w += (size_t)M * QKVLD * 2;
    __bf16* wqkvT = (__bf16*)w;  w += (size_t)QKVLD * C_ * 2;
    __bf16* wpT   = (__bf16*)w;  w += (size_t)C_ * C_ * 2;
    __bf16* vt    = (__bf16*)w;  w += (size_t)M * NKV_ * HD_ * 2;
    __bf16* y     = (__bf16*)w;  w += (size_t)M * C_ * 2;
    float*  pOB   = (float*)w;
    float*  pOA   = (float*)xb;
    float*  pLA   = (float*)wqkvT;
    float*  pLB   = pLA + 8 * 32 * 128;

    // fused preprocessing (cast + both weight transposes): 1 launch
    prep<<<14336, 256, 0, stream>>>(x, Wq, Wk, Wv, Wp, xb, wqkvT, wpT);

    // fused QKV projection + RoPE/RMSNorm epilogue (XCD-chunked; grid 768)
    gemm_bt<__bf16, true><<<dim3(QKVLD / 128, M / 128), 256, 0, stream>>>(
        xb, wqkvT, qkv, M, QKVLD, C_, QKVLD, cosb, sinb);

    // V transpose only (rope now fused into the GEMM epilogue)
    vtrans<<<512, 256, 0, stream>>>(qkv, vt);

    // flash attention v10 + separate combine
    attn32<<<512, 256, 0, stream>>>(qkv, vt, y, pOA, pOB, pLA, pLB);
    attn_combine<<<256, 256, 0, stream>>>(pOA, pOB, pLA, pLB, y);

    // output projection (fp32 out, XCD-chunked; grid 512)
    gemm_bt<float, false><<<dim3(C_ / 128, M / 128), 256, 0, stream>>>(
        y, wpT, out, M, C_, C_, C_, nullptr, nullptr);
}